// Round 1
// baseline (572.703 us; speedup 1.0000x reference)
//
#include <hip/hip_runtime.h>
#include <math.h>

// Problem constants
#define kN 50000
#define kE 800000
#define kM 4
#define kH 4
#define kC 32
#define kIN 256
#define kD 128   // kH*kC

typedef __attribute__((ext_vector_type(8))) short bf16x8;
typedef __attribute__((ext_vector_type(4))) float f32x4;

__device__ __forceinline__ unsigned int f2bf_pack(float a, float b) {
    unsigned ua = __float_as_uint(a);
    ua += 0x7fffu + ((ua >> 16) & 1u);          // RNE
    unsigned ub = __float_as_uint(b);
    ub += 0x7fffu + ((ub >> 16) & 1u);
    return (ua >> 16) | (ub & 0xffff0000u);
}
__device__ __forceinline__ unsigned short f2bf(float x) {
    unsigned u = __float_as_uint(x);
    u += 0x7fffu + ((u >> 16) & 1u);
    return (unsigned short)(u >> 16);
}

// ---------------------------------------------------------------------------
// Wt16[col][k] = bf16(W[k][col])  (128 cols x 256 k)
__global__ void k_wcast(const float* __restrict__ W, unsigned short* __restrict__ Wt16) {
    const int col = blockIdx.x;        // 0..127
    const int k = threadIdx.x;         // 0..255
    Wt16[(size_t)col * kIN + k] = f2bf(W[(size_t)k * kD + col]);
}

// ---------------------------------------------------------------------------
// FUSED: blocks [0,GEMMB) = MFMA bf16 GEMM (h16 = relu(feats@W+b));
//        blocks [GEMMB, GEMMB+COUNTB) = CSR degree count (independent root).
#define GEMMB ((kN + 127) / 128)          // 391
#define COUNTB (kM * kE / 4 / 256)        // 3125
__global__ __launch_bounds__(256) void k_gemmcount(const float* __restrict__ feats,
                                                   const unsigned short* __restrict__ Wt16,
                                                   const float* __restrict__ b,
                                                   unsigned short* __restrict__ h16,
                                                   const int* __restrict__ ei,
                                                   int* __restrict__ cnt) {
    __shared__ unsigned short fr16[128 * 32];   // 8 KB: A chunk [row][32k]
    const int t = threadIdx.x;

    if (blockIdx.x >= GEMMB) {
        // ---- degree count: 4 edges per thread via int4 ----
        const int i = (blockIdx.x - GEMMB) * 256 + t;
        const int m = i / (kE / 4);
        const int el4 = i - m * (kE / 4);
        const int4 d = *reinterpret_cast<const int4*>(ei + (size_t)m * 2 * kE + kE + el4 * 4);
        atomicAdd(&cnt[m * kN + d.x], 1);
        atomicAdd(&cnt[m * kN + d.y], 1);
        atomicAdd(&cnt[m * kN + d.z], 1);
        atomicAdd(&cnt[m * kN + d.w], 1);
        return;
    }

    // ---- MFMA GEMM ----
    const int lane = t & 63;
    const int wave = t >> 6;
    const int q = lane >> 4;           // quad 0..3
    const int m16 = lane & 15;
    const int wrow = (wave >> 1) * 64;
    const int wcol = (wave & 1) * 64;
    const int rowbase = blockIdx.x * 128;

    f32x4 acc[4][4];
#pragma unroll
    for (int i = 0; i < 4; i++)
#pragma unroll
        for (int j = 0; j < 4; j++) acc[i][j] = (f32x4){0.f, 0.f, 0.f, 0.f};

    const int srow = t >> 3;           // staging: 32 rows per pass
    const int sk4 = t & 7;             // float4 slot along k (8 slots = 32 k)

    for (int kc = 0; kc < kIN; kc += 32) {
        __syncthreads();
#pragma unroll
        for (int it = 0; it < 4; it++) {
            const int row = srow + it * 32;
            const int rg = rowbase + row;
            float4 v = make_float4(0.f, 0.f, 0.f, 0.f);
            if (rg < kN)
                v = *reinterpret_cast<const float4*>(feats + (size_t)rg * kIN + kc + sk4 * 4);
            uint2 p;
            p.x = f2bf_pack(v.x, v.y);
            p.y = f2bf_pack(v.z, v.w);
            *reinterpret_cast<uint2*>(&fr16[row * 32 + sk4 * 4]) = p;
        }
        __syncthreads();

        bf16x8 afr[4], bfr[4];
#pragma unroll
        for (int ri = 0; ri < 4; ri++)
            afr[ri] = *reinterpret_cast<const bf16x8*>(
                &fr16[(wrow + ri * 16 + m16) * 32 + q * 8]);
#pragma unroll
        for (int ci = 0; ci < 4; ci++)
            bfr[ci] = *reinterpret_cast<const bf16x8*>(
                Wt16 + (size_t)(wcol + ci * 16 + m16) * kIN + kc + q * 8);
#pragma unroll
        for (int ri = 0; ri < 4; ri++)
#pragma unroll
            for (int ci = 0; ci < 4; ci++)
                acc[ri][ci] = __builtin_amdgcn_mfma_f32_16x16x32_bf16(
                    afr[ri], bfr[ci], acc[ri][ci], 0, 0, 0);
    }

    float bcol[4];
#pragma unroll
    for (int ci = 0; ci < 4; ci++) bcol[ci] = b[wcol + ci * 16 + m16];

#pragma unroll
    for (int ri = 0; ri < 4; ri++) {
#pragma unroll
        for (int reg = 0; reg < 4; reg++) {
            const int row = rowbase + wrow + ri * 16 + q * 4 + reg;
            if (row < kN) {
#pragma unroll
                for (int ci = 0; ci < 4; ci++) {
                    const int col = wcol + ci * 16 + m16;
                    const float v = fmaxf(acc[ri][ci][reg] + bcol[ci], 0.f);
                    h16[(size_t)row * kD + col] = f2bf(v);
                }
            }
        }
    }
}

// ---------------------------------------------------------------------------
// 3-phase parallel scan blocks
#define SCB 2048
#define SCBLOCKS ((kM * kN + SCB - 1) / SCB)   // 98

// FUSED: blocks [0,SLRB) = per-node attention scalars; [SLRB, SLRB+SCBLOCKS) = bsum.
#define SLRB ((kN * kH + 255) / 256)           // 782
__global__ __launch_bounds__(256) void k_slrsum(const unsigned short* __restrict__ h16,
                                                const float* __restrict__ attn,
                                                float* __restrict__ sl, float* __restrict__ sr,
                                                const int* __restrict__ cnt,
                                                int* __restrict__ bsum) {
    const int t = threadIdx.x;
    if (blockIdx.x >= SLRB) {
        // ---- bsum ----
        const int base = (blockIdx.x - SLRB) * SCB;
        int s = 0;
#pragma unroll
        for (int i = 0; i < 8; i++) {
            const int g = base + t * 8 + i;
            if (g < kM * kN) s += cnt[g];
        }
#pragma unroll
        for (int d = 1; d < 64; d <<= 1) s += __shfl_xor(s, d);
        __shared__ int ws[4];
        if ((t & 63) == 0) ws[t >> 6] = s;
        __syncthreads();
        if (t == 0) bsum[blockIdx.x - SLRB] = ws[0] + ws[1] + ws[2] + ws[3];
        return;
    }
    // ---- slr ----
    const int id = blockIdx.x * 256 + t;
    if (id >= kN * kH) return;
    const int n = id >> 2;
    const int hh = id & 3;
    const unsigned int* hu =
        reinterpret_cast<const unsigned int*>(h16 + (size_t)n * kD + hh * kC);
    unsigned int u[16];
    uint4 u4;
#pragma unroll
    for (int i = 0; i < 4; i++) {
        u4 = reinterpret_cast<const uint4*>(hu)[i];
        u[i * 4 + 0] = u4.x; u[i * 4 + 1] = u4.y; u[i * 4 + 2] = u4.z; u[i * 4 + 3] = u4.w;
    }
    float f0[16], f1[16];
#pragma unroll
    for (int c = 0; c < 16; c++) {
        f0[c] = __uint_as_float(u[c] << 16);
        f1[c] = __uint_as_float(u[c] & 0xffff0000u);
    }
#pragma unroll
    for (int m = 0; m < kM; m++) {
        const float2* al = reinterpret_cast<const float2*>(attn + (m * kH + hh) * 2 * kC);
        const float2* ar = al + 16;
        float s0 = 0.f, s1 = 0.f;
#pragma unroll
        for (int c = 0; c < 16; c++) {
            const float2 a = al[c], r = ar[c];
            s0 += f0[c] * a.x + f1[c] * a.y;
            s1 += f0[c] * r.x + f1[c] * r.y;
        }
        sl[((size_t)m * kN + n) * kH + hh] = s0;
        sr[((size_t)m * kN + n) * kH + hh] = s1;
    }
}

__global__ __launch_bounds__(128) void k_bscan(const int* __restrict__ bsum,
                                               int* __restrict__ bpre,
                                               int* __restrict__ offs) {
    const int t = threadIdx.x;
    const int lane = t & 63, wid = t >> 6;
    int v = (t < SCBLOCKS) ? bsum[t] : 0;
    int incl = v;
#pragma unroll
    for (int d = 1; d < 64; d <<= 1) {
        const int x = __shfl_up(incl, d);
        if (lane >= d) incl += x;
    }
    __shared__ int wt[2];
    if (lane == 63) wt[wid] = incl;
    __syncthreads();
    const int add = (wid == 1) ? wt[0] : 0;
    if (t < SCBLOCKS) bpre[t] = incl - v + add;
    if (t < kM) offs[t * (kN + 1) + kN] = kE;   // per-m sentinel
}

__global__ __launch_bounds__(256) void k_scanout(const int* __restrict__ cnt,
                                                 const int* __restrict__ bpre,
                                                 int* __restrict__ offs) {
    const int base = blockIdx.x * SCB;
    const int t = threadIdx.x;
    const int lane = t & 63, wid = t >> 6;
    int v[8];
    int s = 0;
#pragma unroll
    for (int i = 0; i < 8; i++) {
        const int g = base + t * 8 + i;
        v[i] = (g < kM * kN) ? cnt[g] : 0;
        s += v[i];
    }
    int incl = s;
#pragma unroll
    for (int d = 1; d < 64; d <<= 1) {
        const int x = __shfl_up(incl, d);
        if (lane >= d) incl += x;
    }
    __shared__ int wt[4];
    if (lane == 63) wt[wid] = incl;
    __syncthreads();
    int woff = 0;
#pragma unroll
    for (int i = 0; i < 4; i++)
        if (i < wid) woff += wt[i];
    int run = bpre[blockIdx.x] + woff + (incl - s);
#pragma unroll
    for (int i = 0; i < 8; i++) {
        const int g = base + t * 8 + i;
        if (g < kM * kN) {
            const int m = g / kN;
            const int il = g - m * kN;
            offs[m * (kN + 1) + il] = run - m * kE;
            run += v[i];
        }
    }
}

// ---------------------------------------------------------------------------
// Two-phase bucket sort replacing the one-pass scatter.
#define NBK 98                        // buckets: dst>>9, 512 dsts each
#define PAB ((kE + 4095) / 4096)      // 196 chunks per metapath
__global__ __launch_bounds__(256) void k_bucket(const int* __restrict__ ei,
                                                const int* __restrict__ offs,
                                                int* __restrict__ bcur,
                                                unsigned int* __restrict__ pairs) {
    __shared__ int hist[NBK], base[NBK], h2[NBK], bstart[NBK];
    const int t = threadIdx.x;
    const int m = blockIdx.x / PAB;
    const int chunk = blockIdx.x - m * PAB;
    const int e0 = chunk * 4096;
    for (int j = t; j < NBK; j += 256) { hist[j] = 0; h2[j] = 0; }
    __syncthreads();
    int src[16], dst[16];
#pragma unroll
    for (int i = 0; i < 16; i++) {
        const int e = e0 + i * 256 + t;
        const int eok = (e < kE) ? e : 0;
        src[i] = ei[(size_t)m * 2 * kE + eok];
        dst[i] = (e < kE) ? ei[(size_t)m * 2 * kE + kE + eok] : -1;
    }
#pragma unroll
    for (int i = 0; i < 16; i++)
        if (dst[i] >= 0) atomicAdd(&hist[dst[i] >> 9], 1);
    __syncthreads();
    for (int j = t; j < NBK; j += 256) {
        base[j] = atomicAdd(&bcur[m * NBK + j], hist[j]);
        bstart[j] = offs[m * (kN + 1) + (j << 9)];
    }
    __syncthreads();
#pragma unroll
    for (int i = 0; i < 16; i++) {
        if (dst[i] >= 0) {
            const int bk = dst[i] >> 9;
            const int slot = base[bk] + atomicAdd(&h2[bk], 1);
            pairs[(size_t)m * kE + bstart[bk] + slot] =
                ((unsigned int)(dst[i] & 511) << 16) | (unsigned int)src[i];
        }
    }
}

// Phase B: one block per (m,bucket) -> srcsort writes confined to a 32 KB
// window with a SINGLE writer block.
__global__ __launch_bounds__(256) void k_sortb(const unsigned int* __restrict__ pairs,
                                               const int* __restrict__ offs,
                                               int* __restrict__ cur,
                                               int* __restrict__ srcsort) {
    const int t = threadIdx.x;
    const int m = blockIdx.x / NBK;
    const int bk = blockIdx.x - m * NBK;
    const int bs = bk << 9;
    const int be = (bs + 512 < kN) ? (bs + 512) : kN;
    const int* __restrict__ om = offs + m * (kN + 1);
    const int start = om[bs];
    const int end = om[be];
    int* __restrict__ cm = cur + m * kN;
    for (int c = start; c < end; c += 2048) {
        unsigned int v[8]; int pos[8]; bool ok[8];
#pragma unroll
        for (int j = 0; j < 8; j++) {
            const int idx = c + j * 256 + t;
            ok[j] = idx < end;
            v[j] = pairs[(size_t)m * kE + (ok[j] ? idx : start)];
        }
#pragma unroll
        for (int j = 0; j < 8; j++) {
            if (ok[j]) {
                const int d = bs + (int)(v[j] >> 16);
                pos[j] = om[d] + atomicAdd(&cm[d], 1);
            }
        }
#pragma unroll
        for (int j = 0; j < 8; j++)
            if (ok[j]) srcsort[(size_t)m * kE + pos[j]] = (int)(v[j] & 0xffffu);
    }
}

// ---------------------------------------------------------------------------
// aggregation (R8: latency-pipelined version).
// Changes vs R7:
//  - edge ids move lane->wave via readlane (SGPR), no sids LDS round trip;
//  - the 16 h16 row-gathers are issued BEFORE the srv/exp/LDS weight phase,
//    overlapping L3 gather latency with the weight machinery;
//  - my prefetched 2 chunks ahead, srv 1 chunk ahead (over-read into the
//    next segment / zeroed slack is safe: invalid slots get weight 0);
//  - unified branch-free main+tail loop (cndmask on w), no id clamping.
#define CH 16
__global__ __launch_bounds__(256) void k_agg(const unsigned short* __restrict__ h16,
                                             const float* __restrict__ sl,
                                             const float* __restrict__ sr,
                                             const int* __restrict__ offs,
                                             const int* __restrict__ srcsort,
                                             const float* __restrict__ ral,
                                             const float* __restrict__ rar,
                                             const float* __restrict__ rbias,
                                             float* __restrict__ out) {
    const int dst = blockIdx.x;
    const int t = threadIdx.x;
    const int m = t >> 6;
    const int l = t & 63;
    const int hh = l >> 4;        // head for this lane
    const int jj = l & 15;        // edge slot this lane computes the weight for
    const int e0 = l * 2;         // channel pair e0, e0+1

    __shared__ float smres[kM][kD];
    __shared__ float swts[kM][64];

    const int beg = offs[m * (kN + 1) + dst];
    const int cnt = offs[m * (kN + 1) + dst + 1] - beg;
    const float sl_h = sl[((size_t)m * kN + dst) * kH + hh];
    const int* __restrict__ sbase = srcsort + (size_t)m * kE + beg;
    const char* __restrict__ hb = (const char*)h16;
    const char* __restrict__ srb = (const char*)(sr + (size_t)m * kN * kH);
    const unsigned int ebyte = (unsigned int)(e0 << 1);
    const unsigned int hbyte = (unsigned int)(hh << 2);

    float sum = 0.f, a0 = 0.f, a1 = 0.f;

    // prologue prefetch (over-read safe: next segment ids are valid rows,
    // global slack is zeroed; weights for those slots are forced to 0)
    int my0 = sbase[jj];
    int my1 = sbase[CH + jj];
    float srv = *reinterpret_cast<const float*>(
        srb + (((unsigned int)my0 << 4) + hbyte));

    for (int c = 0; c < cnt; c += CH) {
        // ids -> wave-uniform SGPRs, then issue the row gathers immediately
        int sj[CH];
#pragma unroll
        for (int j = 0; j < CH; j++) sj[j] = __builtin_amdgcn_readlane(my0, j);
        unsigned int u[CH];
#pragma unroll
        for (int j = 0; j < CH; j++)
            u[j] = *reinterpret_cast<const unsigned int*>(
                hb + (((size_t)(unsigned int)sj[j] << 8) + ebyte));

        // weight phase (gathers in flight underneath)
        float x = sl_h + srv;
        x = x > 0.f ? x : 0.2f * x;            // LeakyReLU(0.2)
        const float w = (c + jj < cnt) ? __expf(x) : 0.f;
        sum += w;
        swts[m][l] = w;
        __builtin_amdgcn_wave_barrier();
        const float4 w0 = *reinterpret_cast<const float4*>(&swts[m][hh * 16]);
        const float4 w1 = *reinterpret_cast<const float4*>(&swts[m][hh * 16 + 4]);
        const float4 w2 = *reinterpret_cast<const float4*>(&swts[m][hh * 16 + 8]);
        const float4 w3 = *reinterpret_cast<const float4*>(&swts[m][hh * 16 + 12]);
        __builtin_amdgcn_wave_barrier();

        // software pipeline: my 2 chunks ahead, srv 1 chunk ahead
        my0 = my1;
        my1 = sbase[c + 2 * CH + jj];
        srv = *reinterpret_cast<const float*>(
            srb + (((unsigned int)my0 << 4) + hbyte));

        // consume gathers
        const float wj[CH] = {w0.x, w0.y, w0.z, w0.w, w1.x, w1.y, w1.z, w1.w,
                              w2.x, w2.y, w2.z, w2.w, w3.x, w3.y, w3.z, w3.w};
#pragma unroll
        for (int j = 0; j < CH; j++) {
            a0 += wj[j] * __uint_as_float(u[j] << 16);
            a1 += wj[j] * __uint_as_float(u[j] & 0xffff0000u);
        }
    }

    sum += __shfl_xor(sum, 1);
    sum += __shfl_xor(sum, 2);
    sum += __shfl_xor(sum, 4);
    sum += __shfl_xor(sum, 8);
    const float inv = 1.0f / (sum + 1e-16f);
    smres[m][e0] = a0 * inv;
    smres[m][e0 + 1] = a1 * inv;
    __syncthreads();

    if (m == 0) {
        const unsigned int ud = *reinterpret_cast<const unsigned int*>(
            hb + (((unsigned int)dst << 8) + ebyte));
        const float hd0 = __uint_as_float(ud << 16);
        const float hd1 = __uint_as_float(ud & 0xffff0000u);
        const float bl0 = fmaxf(hd0 * ral[e0], 0.f);
        const float bl1 = fmaxf(hd1 * ral[e0 + 1], 0.f);
        float emb0[5], emb1[5], beta[5];
#pragma unroll
        for (int r = 0; r < 5; r++) {
            const float x0 = (r < 4) ? smres[r][e0] : hd0;
            const float x1 = (r < 4) ? smres[r][e0 + 1] : hd1;
            emb0[r] = x0;
            emb1[r] = x1;
            const float br0 = fmaxf(x0 * rar[r * kD + e0], 0.f);
            const float br1 = fmaxf(x1 * rar[r * kD + e0 + 1], 0.f);
            float p = bl0 * br0 + bl1 * br1;
            p += __shfl_xor(p, 1);
            p += __shfl_xor(p, 2);
            p += __shfl_xor(p, 4);
            p += __shfl_xor(p, 8);
            beta[r] = p + rbias[r];
        }
        float mx = beta[0];
#pragma unroll
        for (int r = 1; r < 5; r++) mx = fmaxf(mx, beta[r]);
        float s = 0.f, wgt[5];
#pragma unroll
        for (int r = 0; r < 5; r++) { wgt[r] = __expf(beta[r] - mx); s += wgt[r]; }
        const float invb = 1.f / s;
        float o0 = 0.f, o1 = 0.f;
#pragma unroll
        for (int r = 0; r < 5; r++) { o0 += emb0[r] * wgt[r]; o1 += emb1[r] * wgt[r]; }
        out[(size_t)dst * kD + e0] = fmaxf(o0 * invb, 0.f);
        out[(size_t)dst * kD + e0 + 1] = fmaxf(o1 * invb, 0.f);
    }
}

// ---------------------------------------------------------------------------
extern "C" void kernel_launch(void* const* d_in, const int* in_sizes, int n_in,
                              void* d_out, int out_size, void* d_ws, size_t ws_size,
                              hipStream_t stream) {
    const float* feats = (const float*)d_in[0];
    const int* ei      = (const int*)d_in[1];
    const float* W     = (const float*)d_in[2];
    const float* b     = (const float*)d_in[3];
    const float* attn  = (const float*)d_in[4];
    const float* ral   = (const float*)d_in[5];
    const float* rar   = (const float*)d_in[6];
    const float* rbias = (const float*)d_in[7];
    float* out = (float*)d_out;

    char* ws = (char*)d_ws;
    size_t off = 0;
    auto alloc = [&](size_t bytes) -> void* {
        void* p = ws + off;
        off = (off + bytes + 255) & ~(size_t)255;
        return p;
    };
    unsigned short* h16 = (unsigned short*)alloc(sizeof(short) * (size_t)kN * kD); // 12.8 MB
    unsigned short* Wt16= (unsigned short*)alloc(sizeof(short) * (size_t)kD * kIN); // 64 KB
    float* sl   = (float*)alloc(sizeof(float) * (size_t)kM * kN * kH);         // 3.2 MB
    float* sr   = (float*)alloc(sizeof(float) * (size_t)kM * kN * kH);         // 3.2 MB
    int* cnt    = (int*)alloc(sizeof(int) * ((size_t)2 * kM * kN + 512));      // cnt+cur+bcur
    int* cur    = cnt + (size_t)kM * kN;
    int* bcur   = cnt + (size_t)2 * kM * kN;                                   // kM*NBK = 392
    int* offs   = (int*)alloc(sizeof(int) * (size_t)kM * (kN + 1));
    int* srcsort= (int*)alloc(sizeof(int) * ((size_t)kM * kE + 64));           // + zeroed slack
    unsigned int* pairs = (unsigned int*)alloc(sizeof(int) * (size_t)kM * kE); // 12.8 MB
    int* bsum   = (int*)alloc(sizeof(int) * SCBLOCKS);
    int* bpre   = (int*)alloc(sizeof(int) * 128);

    hipMemsetAsync(cnt, 0, sizeof(int) * ((size_t)2 * kM * kN + 512), stream);
    hipMemsetAsync(srcsort + (size_t)kM * kE, 0, sizeof(int) * 64, stream);
    k_wcast<<<kD, kIN, 0, stream>>>(W, Wt16);
    k_gemmcount<<<GEMMB + COUNTB, 256, 0, stream>>>(feats, Wt16, b, h16, ei, cnt);
    k_slrsum<<<SLRB + SCBLOCKS, 256, 0, stream>>>(h16, attn, sl, sr, cnt, bsum);
    k_bscan<<<1, 128, 0, stream>>>(bsum, bpre, offs);
    k_scanout<<<SCBLOCKS, 256, 0, stream>>>(cnt, bpre, offs);
    k_bucket<<<kM * PAB, 256, 0, stream>>>(ei, offs, bcur, pairs);
    k_sortb<<<kM * NBK, 256, 0, stream>>>(pairs, offs, cur, srcsort);
    k_agg<<<kN, 256, 0, stream>>>(h16, sl, sr, offs, srcsort, ral, rar, rbias, out);
}

// Round 2
// 536.262 us; speedup vs baseline: 1.0680x; 1.0680x over previous
//
#include <hip/hip_runtime.h>
#include <math.h>

// Problem constants
#define kN 50000
#define kE 800000
#define kM 4
#define kH 4
#define kC 32
#define kIN 256
#define kD 128   // kH*kC

typedef __attribute__((ext_vector_type(8))) short bf16x8;
typedef __attribute__((ext_vector_type(4))) float f32x4;

__device__ __forceinline__ unsigned int f2bf_pack(float a, float b) {
    unsigned ua = __float_as_uint(a);
    ua += 0x7fffu + ((ua >> 16) & 1u);          // RNE
    unsigned ub = __float_as_uint(b);
    ub += 0x7fffu + ((ub >> 16) & 1u);
    return (ua >> 16) | (ub & 0xffff0000u);
}
__device__ __forceinline__ unsigned short f2bf(float x) {
    unsigned u = __float_as_uint(x);
    u += 0x7fffu + ((u >> 16) & 1u);
    return (unsigned short)(u >> 16);
}

// ---------------------------------------------------------------------------
// Wt16[col][k] = bf16(W[k][col])  (128 cols x 256 k)
__global__ void k_wcast(const float* __restrict__ W, unsigned short* __restrict__ Wt16) {
    const int col = blockIdx.x;        // 0..127
    const int k = threadIdx.x;         // 0..255
    Wt16[(size_t)col * kIN + k] = f2bf(W[(size_t)k * kD + col]);
}

// ---------------------------------------------------------------------------
// FUSED: blocks [0,GEMMB) = MFMA bf16 GEMM (h16 = relu(feats@W+b));
//        blocks [GEMMB, GEMMB+COUNTB) = CSR degree count (independent root).
#define GEMMB ((kN + 127) / 128)          // 391
#define COUNTB (kM * kE / 4 / 256)        // 3125
__global__ __launch_bounds__(256) void k_gemmcount(const float* __restrict__ feats,
                                                   const unsigned short* __restrict__ Wt16,
                                                   const float* __restrict__ b,
                                                   unsigned short* __restrict__ h16,
                                                   const int* __restrict__ ei,
                                                   int* __restrict__ cnt) {
    __shared__ unsigned short fr16[128 * 32];   // 8 KB: A chunk [row][32k]
    const int t = threadIdx.x;

    if (blockIdx.x >= GEMMB) {
        // ---- degree count: 4 edges per thread via int4 ----
        const int i = (blockIdx.x - GEMMB) * 256 + t;
        const int m = i / (kE / 4);
        const int el4 = i - m * (kE / 4);
        const int4 d = *reinterpret_cast<const int4*>(ei + (size_t)m * 2 * kE + kE + el4 * 4);
        atomicAdd(&cnt[m * kN + d.x], 1);
        atomicAdd(&cnt[m * kN + d.y], 1);
        atomicAdd(&cnt[m * kN + d.z], 1);
        atomicAdd(&cnt[m * kN + d.w], 1);
        return;
    }

    // ---- MFMA GEMM ----
    const int lane = t & 63;
    const int wave = t >> 6;
    const int q = lane >> 4;           // quad 0..3
    const int m16 = lane & 15;
    const int wrow = (wave >> 1) * 64;
    const int wcol = (wave & 1) * 64;
    const int rowbase = blockIdx.x * 128;

    f32x4 acc[4][4];
#pragma unroll
    for (int i = 0; i < 4; i++)
#pragma unroll
        for (int j = 0; j < 4; j++) acc[i][j] = (f32x4){0.f, 0.f, 0.f, 0.f};

    const int srow = t >> 3;           // staging: 32 rows per pass
    const int sk4 = t & 7;             // float4 slot along k (8 slots = 32 k)

    for (int kc = 0; kc < kIN; kc += 32) {
        __syncthreads();
#pragma unroll
        for (int it = 0; it < 4; it++) {
            const int row = srow + it * 32;
            const int rg = rowbase + row;
            float4 v = make_float4(0.f, 0.f, 0.f, 0.f);
            if (rg < kN)
                v = *reinterpret_cast<const float4*>(feats + (size_t)rg * kIN + kc + sk4 * 4);
            uint2 p;
            p.x = f2bf_pack(v.x, v.y);
            p.y = f2bf_pack(v.z, v.w);
            *reinterpret_cast<uint2*>(&fr16[row * 32 + sk4 * 4]) = p;
        }
        __syncthreads();

        bf16x8 afr[4], bfr[4];
#pragma unroll
        for (int ri = 0; ri < 4; ri++)
            afr[ri] = *reinterpret_cast<const bf16x8*>(
                &fr16[(wrow + ri * 16 + m16) * 32 + q * 8]);
#pragma unroll
        for (int ci = 0; ci < 4; ci++)
            bfr[ci] = *reinterpret_cast<const bf16x8*>(
                Wt16 + (size_t)(wcol + ci * 16 + m16) * kIN + kc + q * 8);
#pragma unroll
        for (int ri = 0; ri < 4; ri++)
#pragma unroll
            for (int ci = 0; ci < 4; ci++)
                acc[ri][ci] = __builtin_amdgcn_mfma_f32_16x16x32_bf16(
                    afr[ri], bfr[ci], acc[ri][ci], 0, 0, 0);
    }

    float bcol[4];
#pragma unroll
    for (int ci = 0; ci < 4; ci++) bcol[ci] = b[wcol + ci * 16 + m16];

#pragma unroll
    for (int ri = 0; ri < 4; ri++) {
#pragma unroll
        for (int reg = 0; reg < 4; reg++) {
            const int row = rowbase + wrow + ri * 16 + q * 4 + reg;
            if (row < kN) {
#pragma unroll
                for (int ci = 0; ci < 4; ci++) {
                    const int col = wcol + ci * 16 + m16;
                    const float v = fmaxf(acc[ri][ci][reg] + bcol[ci], 0.f);
                    h16[(size_t)row * kD + col] = f2bf(v);
                }
            }
        }
    }
}

// ---------------------------------------------------------------------------
// 3-phase parallel scan blocks
#define SCB 2048
#define SCBLOCKS ((kM * kN + SCB - 1) / SCB)   // 98

// FUSED: blocks [0,SLRB) = per-node attention scalars; [SLRB, SLRB+SCBLOCKS) = bsum.
#define SLRB ((kN * kH + 255) / 256)           // 782
__global__ __launch_bounds__(256) void k_slrsum(const unsigned short* __restrict__ h16,
                                                const float* __restrict__ attn,
                                                float* __restrict__ sl, float* __restrict__ sr,
                                                const int* __restrict__ cnt,
                                                int* __restrict__ bsum) {
    const int t = threadIdx.x;
    if (blockIdx.x >= SLRB) {
        // ---- bsum ----
        const int base = (blockIdx.x - SLRB) * SCB;
        int s = 0;
#pragma unroll
        for (int i = 0; i < 8; i++) {
            const int g = base + t * 8 + i;
            if (g < kM * kN) s += cnt[g];
        }
#pragma unroll
        for (int d = 1; d < 64; d <<= 1) s += __shfl_xor(s, d);
        __shared__ int ws[4];
        if ((t & 63) == 0) ws[t >> 6] = s;
        __syncthreads();
        if (t == 0) bsum[blockIdx.x - SLRB] = ws[0] + ws[1] + ws[2] + ws[3];
        return;
    }
    // ---- slr ----
    const int id = blockIdx.x * 256 + t;
    if (id >= kN * kH) return;
    const int n = id >> 2;
    const int hh = id & 3;
    const unsigned int* hu =
        reinterpret_cast<const unsigned int*>(h16 + (size_t)n * kD + hh * kC);
    unsigned int u[16];
    uint4 u4;
#pragma unroll
    for (int i = 0; i < 4; i++) {
        u4 = reinterpret_cast<const uint4*>(hu)[i];
        u[i * 4 + 0] = u4.x; u[i * 4 + 1] = u4.y; u[i * 4 + 2] = u4.z; u[i * 4 + 3] = u4.w;
    }
    float f0[16], f1[16];
#pragma unroll
    for (int c = 0; c < 16; c++) {
        f0[c] = __uint_as_float(u[c] << 16);
        f1[c] = __uint_as_float(u[c] & 0xffff0000u);
    }
#pragma unroll
    for (int m = 0; m < kM; m++) {
        const float2* al = reinterpret_cast<const float2*>(attn + (m * kH + hh) * 2 * kC);
        const float2* ar = al + 16;
        float s0 = 0.f, s1 = 0.f;
#pragma unroll
        for (int c = 0; c < 16; c++) {
            const float2 a = al[c], r = ar[c];
            s0 += f0[c] * a.x + f1[c] * a.y;
            s1 += f0[c] * r.x + f1[c] * r.y;
        }
        sl[((size_t)m * kN + n) * kH + hh] = s0;
        sr[((size_t)m * kN + n) * kH + hh] = s1;
    }
}

__global__ __launch_bounds__(128) void k_bscan(const int* __restrict__ bsum,
                                               int* __restrict__ bpre,
                                               int* __restrict__ offs) {
    const int t = threadIdx.x;
    const int lane = t & 63, wid = t >> 6;
    int v = (t < SCBLOCKS) ? bsum[t] : 0;
    int incl = v;
#pragma unroll
    for (int d = 1; d < 64; d <<= 1) {
        const int x = __shfl_up(incl, d);
        if (lane >= d) incl += x;
    }
    __shared__ int wt[2];
    if (lane == 63) wt[wid] = incl;
    __syncthreads();
    const int add = (wid == 1) ? wt[0] : 0;
    if (t < SCBLOCKS) bpre[t] = incl - v + add;
    if (t < kM) offs[t * (kN + 1) + kN] = kE;   // per-m sentinel
}

__global__ __launch_bounds__(256) void k_scanout(const int* __restrict__ cnt,
                                                 const int* __restrict__ bpre,
                                                 int* __restrict__ offs) {
    const int base = blockIdx.x * SCB;
    const int t = threadIdx.x;
    const int lane = t & 63, wid = t >> 6;
    int v[8];
    int s = 0;
#pragma unroll
    for (int i = 0; i < 8; i++) {
        const int g = base + t * 8 + i;
        v[i] = (g < kM * kN) ? cnt[g] : 0;
        s += v[i];
    }
    int incl = s;
#pragma unroll
    for (int d = 1; d < 64; d <<= 1) {
        const int x = __shfl_up(incl, d);
        if (lane >= d) incl += x;
    }
    __shared__ int wt[4];
    if (lane == 63) wt[wid] = incl;
    __syncthreads();
    int woff = 0;
#pragma unroll
    for (int i = 0; i < 4; i++)
        if (i < wid) woff += wt[i];
    int run = bpre[blockIdx.x] + woff + (incl - s);
#pragma unroll
    for (int i = 0; i < 8; i++) {
        const int g = base + t * 8 + i;
        if (g < kM * kN) {
            const int m = g / kN;
            const int il = g - m * kN;
            offs[m * (kN + 1) + il] = run - m * kE;
            run += v[i];
        }
    }
}

// ---------------------------------------------------------------------------
// Two-phase bucket sort replacing the one-pass scatter.
#define NBK 98                        // buckets: dst>>9, 512 dsts each
#define PAB ((kE + 4095) / 4096)      // 196 chunks per metapath
__global__ __launch_bounds__(256) void k_bucket(const int* __restrict__ ei,
                                                const int* __restrict__ offs,
                                                int* __restrict__ bcur,
                                                unsigned int* __restrict__ pairs) {
    __shared__ int hist[NBK], base[NBK], h2[NBK], bstart[NBK];
    const int t = threadIdx.x;
    const int m = blockIdx.x / PAB;
    const int chunk = blockIdx.x - m * PAB;
    const int e0 = chunk * 4096;
    for (int j = t; j < NBK; j += 256) { hist[j] = 0; h2[j] = 0; }
    __syncthreads();
    int src[16], dst[16];
#pragma unroll
    for (int i = 0; i < 16; i++) {
        const int e = e0 + i * 256 + t;
        const int eok = (e < kE) ? e : 0;
        src[i] = ei[(size_t)m * 2 * kE + eok];
        dst[i] = (e < kE) ? ei[(size_t)m * 2 * kE + kE + eok] : -1;
    }
#pragma unroll
    for (int i = 0; i < 16; i++)
        if (dst[i] >= 0) atomicAdd(&hist[dst[i] >> 9], 1);
    __syncthreads();
    for (int j = t; j < NBK; j += 256) {
        base[j] = atomicAdd(&bcur[m * NBK + j], hist[j]);
        bstart[j] = offs[m * (kN + 1) + (j << 9)];
    }
    __syncthreads();
#pragma unroll
    for (int i = 0; i < 16; i++) {
        if (dst[i] >= 0) {
            const int bk = dst[i] >> 9;
            const int slot = base[bk] + atomicAdd(&h2[bk], 1);
            pairs[(size_t)m * kE + bstart[bk] + slot] =
                ((unsigned int)(dst[i] & 511) << 16) | (unsigned int)src[i];
        }
    }
}

// Phase B: one block per (m,bucket) -> srcsort writes confined to a 32 KB
// window with a SINGLE writer block.
__global__ __launch_bounds__(256) void k_sortb(const unsigned int* __restrict__ pairs,
                                               const int* __restrict__ offs,
                                               int* __restrict__ cur,
                                               int* __restrict__ srcsort) {
    const int t = threadIdx.x;
    const int m = blockIdx.x / NBK;
    const int bk = blockIdx.x - m * NBK;
    const int bs = bk << 9;
    const int be = (bs + 512 < kN) ? (bs + 512) : kN;
    const int* __restrict__ om = offs + m * (kN + 1);
    const int start = om[bs];
    const int end = om[be];
    int* __restrict__ cm = cur + m * kN;
    for (int c = start; c < end; c += 2048) {
        unsigned int v[8]; int pos[8]; bool ok[8];
#pragma unroll
        for (int j = 0; j < 8; j++) {
            const int idx = c + j * 256 + t;
            ok[j] = idx < end;
            v[j] = pairs[(size_t)m * kE + (ok[j] ? idx : start)];
        }
#pragma unroll
        for (int j = 0; j < 8; j++) {
            if (ok[j]) {
                const int d = bs + (int)(v[j] >> 16);
                pos[j] = om[d] + atomicAdd(&cm[d], 1);
            }
        }
#pragma unroll
        for (int j = 0; j < 8; j++)
            if (ok[j]) srcsort[(size_t)m * kE + pos[j]] = (int)(v[j] & 0xffffu);
    }
}

// ---------------------------------------------------------------------------
// aggregation (R9: R8 pipeline + restored R7 tail clamp).
// R8 post-mortem: dropping the tail clamp made dead tail slots gather RANDOM
// h16 rows from the next segment (weight 0, pure waste) -> +155 MB FETCH,
// 159->189 us. R9 keeps the R8 latency pipeline (readlane SGPR ids, gathers
// issued before the weight phase, my/srv prefetch) but clamps dead slots to
// the dst row (hot line) exactly as R7 did. Clamp is wave-uniform
// ((j<nb)?id:dst with literal j, scalar nb) -> s_cselect, ids stay SGPRs.
#define CH 16
__global__ __launch_bounds__(256) void k_agg(const unsigned short* __restrict__ h16,
                                             const float* __restrict__ sl,
                                             const float* __restrict__ sr,
                                             const int* __restrict__ offs,
                                             const int* __restrict__ srcsort,
                                             const float* __restrict__ ral,
                                             const float* __restrict__ rar,
                                             const float* __restrict__ rbias,
                                             float* __restrict__ out) {
    const int dst = blockIdx.x;
    const int t = threadIdx.x;
    const int m = t >> 6;
    const int l = t & 63;
    const int hh = l >> 4;        // head for this lane
    const int jj = l & 15;        // edge slot this lane computes the weight for
    const int e0 = l * 2;         // channel pair e0, e0+1

    __shared__ float smres[kM][kD];
    __shared__ float swts[kM][64];

    const int beg = offs[m * (kN + 1) + dst];
    const int cnt = offs[m * (kN + 1) + dst + 1] - beg;
    const float sl_h = sl[((size_t)m * kN + dst) * kH + hh];
    const int* __restrict__ sbase = srcsort + (size_t)m * kE + beg;
    const char* __restrict__ hb = (const char*)h16;
    const char* __restrict__ srb = (const char*)(sr + (size_t)m * kN * kH);
    const unsigned int ebyte = (unsigned int)(e0 << 1);
    const unsigned int hbyte = (unsigned int)(hh << 2);

    float sum = 0.f, a0 = 0.f, a1 = 0.f;

    // prologue prefetch (over-read safe: next segment ids are valid rows,
    // global slack is zeroed; weights for those slots are forced to 0 and
    // their h16 gathers are clamped to the dst row below)
    int my0 = sbase[jj];
    int my1 = sbase[CH + jj];
    float srv = *reinterpret_cast<const float*>(
        srb + (((unsigned int)my0 << 4) + hbyte));

    for (int c = 0; c < cnt; c += CH) {
        const int nb = cnt - c;   // wave-uniform chunk occupancy
        // ids -> wave-uniform SGPRs (dead slots clamp to dst = hot line),
        // then issue the row gathers immediately
        int sj[CH];
#pragma unroll
        for (int j = 0; j < CH; j++) {
            const int id = __builtin_amdgcn_readlane(my0, j);
            sj[j] = (j < nb) ? id : dst;
        }
        unsigned int u[CH];
#pragma unroll
        for (int j = 0; j < CH; j++)
            u[j] = *reinterpret_cast<const unsigned int*>(
                hb + (((size_t)(unsigned int)sj[j] << 8) + ebyte));

        // weight phase (gathers in flight underneath)
        float x = sl_h + srv;
        x = x > 0.f ? x : 0.2f * x;            // LeakyReLU(0.2)
        const float w = (c + jj < cnt) ? __expf(x) : 0.f;
        sum += w;
        swts[m][l] = w;
        __builtin_amdgcn_wave_barrier();
        const float4 w0 = *reinterpret_cast<const float4*>(&swts[m][hh * 16]);
        const float4 w1 = *reinterpret_cast<const float4*>(&swts[m][hh * 16 + 4]);
        const float4 w2 = *reinterpret_cast<const float4*>(&swts[m][hh * 16 + 8]);
        const float4 w3 = *reinterpret_cast<const float4*>(&swts[m][hh * 16 + 12]);
        __builtin_amdgcn_wave_barrier();

        // software pipeline: my 2 chunks ahead, srv 1 chunk ahead
        my0 = my1;
        my1 = sbase[c + 2 * CH + jj];
        srv = *reinterpret_cast<const float*>(
            srb + (((unsigned int)my0 << 4) + hbyte));

        // consume gathers
        const float wj[CH] = {w0.x, w0.y, w0.z, w0.w, w1.x, w1.y, w1.z, w1.w,
                              w2.x, w2.y, w2.z, w2.w, w3.x, w3.y, w3.z, w3.w};
#pragma unroll
        for (int j = 0; j < CH; j++) {
            a0 += wj[j] * __uint_as_float(u[j] << 16);
            a1 += wj[j] * __uint_as_float(u[j] & 0xffff0000u);
        }
    }

    sum += __shfl_xor(sum, 1);
    sum += __shfl_xor(sum, 2);
    sum += __shfl_xor(sum, 4);
    sum += __shfl_xor(sum, 8);
    const float inv = 1.0f / (sum + 1e-16f);
    smres[m][e0] = a0 * inv;
    smres[m][e0 + 1] = a1 * inv;
    __syncthreads();

    if (m == 0) {
        const unsigned int ud = *reinterpret_cast<const unsigned int*>(
            hb + (((unsigned int)dst << 8) + ebyte));
        const float hd0 = __uint_as_float(ud << 16);
        const float hd1 = __uint_as_float(ud & 0xffff0000u);
        const float bl0 = fmaxf(hd0 * ral[e0], 0.f);
        const float bl1 = fmaxf(hd1 * ral[e0 + 1], 0.f);
        float emb0[5], emb1[5], beta[5];
#pragma unroll
        for (int r = 0; r < 5; r++) {
            const float x0 = (r < 4) ? smres[r][e0] : hd0;
            const float x1 = (r < 4) ? smres[r][e0 + 1] : hd1;
            emb0[r] = x0;
            emb1[r] = x1;
            const float br0 = fmaxf(x0 * rar[r * kD + e0], 0.f);
            const float br1 = fmaxf(x1 * rar[r * kD + e0 + 1], 0.f);
            float p = bl0 * br0 + bl1 * br1;
            p += __shfl_xor(p, 1);
            p += __shfl_xor(p, 2);
            p += __shfl_xor(p, 4);
            p += __shfl_xor(p, 8);
            beta[r] = p + rbias[r];
        }
        float mx = beta[0];
#pragma unroll
        for (int r = 1; r < 5; r++) mx = fmaxf(mx, beta[r]);
        float s = 0.f, wgt[5];
#pragma unroll
        for (int r = 0; r < 5; r++) { wgt[r] = __expf(beta[r] - mx); s += wgt[r]; }
        const float invb = 1.f / s;
        float o0 = 0.f, o1 = 0.f;
#pragma unroll
        for (int r = 0; r < 5; r++) { o0 += emb0[r] * wgt[r]; o1 += emb1[r] * wgt[r]; }
        out[(size_t)dst * kD + e0] = fmaxf(o0 * invb, 0.f);
        out[(size_t)dst * kD + e0 + 1] = fmaxf(o1 * invb, 0.f);
    }
}

// ---------------------------------------------------------------------------
extern "C" void kernel_launch(void* const* d_in, const int* in_sizes, int n_in,
                              void* d_out, int out_size, void* d_ws, size_t ws_size,
                              hipStream_t stream) {
    const float* feats = (const float*)d_in[0];
    const int* ei      = (const int*)d_in[1];
    const float* W     = (const float*)d_in[2];
    const float* b     = (const float*)d_in[3];
    const float* attn  = (const float*)d_in[4];
    const float* ral   = (const float*)d_in[5];
    const float* rar   = (const float*)d_in[6];
    const float* rbias = (const float*)d_in[7];
    float* out = (float*)d_out;

    char* ws = (char*)d_ws;
    size_t off = 0;
    auto alloc = [&](size_t bytes) -> void* {
        void* p = ws + off;
        off = (off + bytes + 255) & ~(size_t)255;
        return p;
    };
    unsigned short* h16 = (unsigned short*)alloc(sizeof(short) * (size_t)kN * kD); // 12.8 MB
    unsigned short* Wt16= (unsigned short*)alloc(sizeof(short) * (size_t)kD * kIN); // 64 KB
    float* sl   = (float*)alloc(sizeof(float) * (size_t)kM * kN * kH);         // 3.2 MB
    float* sr   = (float*)alloc(sizeof(float) * (size_t)kM * kN * kH);         // 3.2 MB
    int* cnt    = (int*)alloc(sizeof(int) * ((size_t)2 * kM * kN + 512));      // cnt+cur+bcur
    int* cur    = cnt + (size_t)kM * kN;
    int* bcur   = cnt + (size_t)2 * kM * kN;                                   // kM*NBK = 392
    int* offs   = (int*)alloc(sizeof(int) * (size_t)kM * (kN + 1));
    int* srcsort= (int*)alloc(sizeof(int) * ((size_t)kM * kE + 64));           // + zeroed slack
    unsigned int* pairs = (unsigned int*)alloc(sizeof(int) * (size_t)kM * kE); // 12.8 MB
    int* bsum   = (int*)alloc(sizeof(int) * SCBLOCKS);
    int* bpre   = (int*)alloc(sizeof(int) * 128);

    hipMemsetAsync(cnt, 0, sizeof(int) * ((size_t)2 * kM * kN + 512), stream);
    hipMemsetAsync(srcsort + (size_t)kM * kE, 0, sizeof(int) * 64, stream);
    k_wcast<<<kD, kIN, 0, stream>>>(W, Wt16);
    k_gemmcount<<<GEMMB + COUNTB, 256, 0, stream>>>(feats, Wt16, b, h16, ei, cnt);
    k_slrsum<<<SLRB + SCBLOCKS, 256, 0, stream>>>(h16, attn, sl, sr, cnt, bsum);
    k_bscan<<<1, 128, 0, stream>>>(bsum, bpre, offs);
    k_scanout<<<SCBLOCKS, 256, 0, stream>>>(cnt, bpre, offs);
    k_bucket<<<kM * PAB, 256, 0, stream>>>(ei, offs, bcur, pairs);
    k_sortb<<<kM * NBK, 256, 0, stream>>>(pairs, offs, cur, srcsort);
    k_agg<<<kN, 256, 0, stream>>>(h16, sl, sr, offs, srcsort, ral, rar, rbias, out);
}

// Round 3
// 521.396 us; speedup vs baseline: 1.0984x; 1.0285x over previous
//
#include <hip/hip_runtime.h>
#include <math.h>

// Problem constants
#define kN 50000
#define kE 800000
#define kM 4
#define kH 4
#define kC 32
#define kIN 256
#define kD 128   // kH*kC

typedef __attribute__((ext_vector_type(8))) short bf16x8;
typedef __attribute__((ext_vector_type(4))) float f32x4;

__device__ __forceinline__ unsigned int f2bf_pack(float a, float b) {
    unsigned ua = __float_as_uint(a);
    ua += 0x7fffu + ((ua >> 16) & 1u);          // RNE
    unsigned ub = __float_as_uint(b);
    ub += 0x7fffu + ((ub >> 16) & 1u);
    return (ua >> 16) | (ub & 0xffff0000u);
}
__device__ __forceinline__ unsigned short f2bf(float x) {
    unsigned u = __float_as_uint(x);
    u += 0x7fffu + ((u >> 16) & 1u);
    return (unsigned short)(u >> 16);
}

// ---------------------------------------------------------------------------
// Wt16[col][k] = bf16(W[k][col])  (128 cols x 256 k)
__global__ void k_wcast(const float* __restrict__ W, unsigned short* __restrict__ Wt16) {
    const int col = blockIdx.x;        // 0..127
    const int k = threadIdx.x;         // 0..255
    Wt16[(size_t)col * kIN + k] = f2bf(W[(size_t)k * kD + col]);
}

// ---------------------------------------------------------------------------
// FUSED: blocks [0,GEMMB) = MFMA bf16 GEMM (h16 = relu(feats@W+b));
//        blocks [GEMMB, GEMMB+COUNTB) = CSR degree count (independent root).
#define GEMMB ((kN + 127) / 128)          // 391
#define COUNTB (kM * kE / 4 / 256)        // 3125
__global__ __launch_bounds__(256) void k_gemmcount(const float* __restrict__ feats,
                                                   const unsigned short* __restrict__ Wt16,
                                                   const float* __restrict__ b,
                                                   unsigned short* __restrict__ h16,
                                                   const int* __restrict__ ei,
                                                   int* __restrict__ cnt) {
    __shared__ unsigned short fr16[128 * 32];   // 8 KB: A chunk [row][32k]
    const int t = threadIdx.x;

    if (blockIdx.x >= GEMMB) {
        // ---- degree count: 4 edges per thread via int4 ----
        const int i = (blockIdx.x - GEMMB) * 256 + t;
        const int m = i / (kE / 4);
        const int el4 = i - m * (kE / 4);
        const int4 d = *reinterpret_cast<const int4*>(ei + (size_t)m * 2 * kE + kE + el4 * 4);
        atomicAdd(&cnt[m * kN + d.x], 1);
        atomicAdd(&cnt[m * kN + d.y], 1);
        atomicAdd(&cnt[m * kN + d.z], 1);
        atomicAdd(&cnt[m * kN + d.w], 1);
        return;
    }

    // ---- MFMA GEMM ----
    const int lane = t & 63;
    const int wave = t >> 6;
    const int q = lane >> 4;           // quad 0..3
    const int m16 = lane & 15;
    const int wrow = (wave >> 1) * 64;
    const int wcol = (wave & 1) * 64;
    const int rowbase = blockIdx.x * 128;

    f32x4 acc[4][4];
#pragma unroll
    for (int i = 0; i < 4; i++)
#pragma unroll
        for (int j = 0; j < 4; j++) acc[i][j] = (f32x4){0.f, 0.f, 0.f, 0.f};

    const int srow = t >> 3;           // staging: 32 rows per pass
    const int sk4 = t & 7;             // float4 slot along k (8 slots = 32 k)

    for (int kc = 0; kc < kIN; kc += 32) {
        __syncthreads();
#pragma unroll
        for (int it = 0; it < 4; it++) {
            const int row = srow + it * 32;
            const int rg = rowbase + row;
            float4 v = make_float4(0.f, 0.f, 0.f, 0.f);
            if (rg < kN)
                v = *reinterpret_cast<const float4*>(feats + (size_t)rg * kIN + kc + sk4 * 4);
            uint2 p;
            p.x = f2bf_pack(v.x, v.y);
            p.y = f2bf_pack(v.z, v.w);
            *reinterpret_cast<uint2*>(&fr16[row * 32 + sk4 * 4]) = p;
        }
        __syncthreads();

        bf16x8 afr[4], bfr[4];
#pragma unroll
        for (int ri = 0; ri < 4; ri++)
            afr[ri] = *reinterpret_cast<const bf16x8*>(
                &fr16[(wrow + ri * 16 + m16) * 32 + q * 8]);
#pragma unroll
        for (int ci = 0; ci < 4; ci++)
            bfr[ci] = *reinterpret_cast<const bf16x8*>(
                Wt16 + (size_t)(wcol + ci * 16 + m16) * kIN + kc + q * 8);
#pragma unroll
        for (int ri = 0; ri < 4; ri++)
#pragma unroll
            for (int ci = 0; ci < 4; ci++)
                acc[ri][ci] = __builtin_amdgcn_mfma_f32_16x16x32_bf16(
                    afr[ri], bfr[ci], acc[ri][ci], 0, 0, 0);
    }

    float bcol[4];
#pragma unroll
    for (int ci = 0; ci < 4; ci++) bcol[ci] = b[wcol + ci * 16 + m16];

#pragma unroll
    for (int ri = 0; ri < 4; ri++) {
#pragma unroll
        for (int reg = 0; reg < 4; reg++) {
            const int row = rowbase + wrow + ri * 16 + q * 4 + reg;
            if (row < kN) {
#pragma unroll
                for (int ci = 0; ci < 4; ci++) {
                    const int col = wcol + ci * 16 + m16;
                    const float v = fmaxf(acc[ri][ci][reg] + bcol[ci], 0.f);
                    h16[(size_t)row * kD + col] = f2bf(v);
                }
            }
        }
    }
}

// ---------------------------------------------------------------------------
// Single-kernel decoupled-lookback scan replacing bsum/bscan/scanout.
// 98 blocks <= 256 CUs -> all co-resident regardless of dispatch order, so the
// lookback spin cannot deadlock. part[b] carries (block_total + 1) as a
// single-word payload+ready flag (0 = not published); device-scope atomics
// make it XCD-coherence-safe.
#define SCB 2048
#define SCBLOCKS ((kM * kN + SCB - 1) / SCB)   // 98
__global__ __launch_bounds__(256) void k_scan(const int* __restrict__ cnt,
                                              int* __restrict__ part,
                                              int* __restrict__ offs) {
    const int b = blockIdx.x;
    const int base = b * SCB;
    const int t = threadIdx.x;
    const int lane = t & 63, wid = t >> 6;
    int v[8];
    int s = 0;
#pragma unroll
    for (int i = 0; i < 8; i++) {
        const int g = base + t * 8 + i;
        v[i] = (g < kM * kN) ? cnt[g] : 0;
        s += v[i];
    }
    int incl = s;
#pragma unroll
    for (int d = 1; d < 64; d <<= 1) {
        const int x = __shfl_up(incl, d);
        if (lane >= d) incl += x;
    }
    __shared__ int wt[4];
    if (lane == 63) wt[wid] = incl;
    __syncthreads();
    int woff = 0;
#pragma unroll
    for (int i = 0; i < 4; i++)
        if (i < wid) woff += wt[i];
    const int total = wt[0] + wt[1] + wt[2] + wt[3];
    if (t == 0) atomicExch(&part[b], total + 1);   // publish payload+flag

    // lookback: thread t polls predecessor t (t < b <= 97)
    int p = 0;
    if (t < b) {
        do { p = atomicAdd(&part[t], 0); } while (p == 0);
        p -= 1;
    }
    int pr = p;
#pragma unroll
    for (int d = 1; d < 64; d <<= 1) pr += __shfl_xor(pr, d);
    __shared__ int ws[4];
    if (lane == 0) ws[wid] = pr;
    __syncthreads();
    const int pre = ws[0] + ws[1] + ws[2] + ws[3];

    int run = pre + woff + (incl - s);
#pragma unroll
    for (int i = 0; i < 8; i++) {
        const int g = base + t * 8 + i;
        if (g < kM * kN) {
            const int m = g / kN;
            const int il = g - m * kN;
            offs[m * (kN + 1) + il] = run - m * kE;
            run += v[i];
        }
    }
    if (b == 0 && t < kM) offs[t * (kN + 1) + kN] = kE;   // per-m sentinel
}

// ---------------------------------------------------------------------------
// Two-phase bucket sort replacing the one-pass scatter.
#define NBK 98                        // buckets: dst>>9, 512 dsts each
#define PAB ((kE + 4095) / 4096)      // 196 chunks per metapath
__global__ __launch_bounds__(256) void k_bucket(const int* __restrict__ ei,
                                                const int* __restrict__ offs,
                                                int* __restrict__ bcur,
                                                unsigned int* __restrict__ pairs) {
    __shared__ int hist[NBK], base[NBK], h2[NBK], bstart[NBK];
    const int t = threadIdx.x;
    const int m = blockIdx.x / PAB;
    const int chunk = blockIdx.x - m * PAB;
    const int e0 = chunk * 4096;
    for (int j = t; j < NBK; j += 256) { hist[j] = 0; h2[j] = 0; }
    __syncthreads();
    int src[16], dst[16];
#pragma unroll
    for (int i = 0; i < 16; i++) {
        const int e = e0 + i * 256 + t;
        const int eok = (e < kE) ? e : 0;
        src[i] = ei[(size_t)m * 2 * kE + eok];
        dst[i] = (e < kE) ? ei[(size_t)m * 2 * kE + kE + eok] : -1;
    }
#pragma unroll
    for (int i = 0; i < 16; i++)
        if (dst[i] >= 0) atomicAdd(&hist[dst[i] >> 9], 1);
    __syncthreads();
    for (int j = t; j < NBK; j += 256) {
        base[j] = atomicAdd(&bcur[m * NBK + j], hist[j]);
        bstart[j] = offs[m * (kN + 1) + (j << 9)];
    }
    __syncthreads();
#pragma unroll
    for (int i = 0; i < 16; i++) {
        if (dst[i] >= 0) {
            const int bk = dst[i] >> 9;
            const int slot = base[bk] + atomicAdd(&h2[bk], 1);
            pairs[(size_t)m * kE + bstart[bk] + slot] =
                ((unsigned int)(dst[i] & 511) << 16) | (unsigned int)src[i];
        }
    }
}

// ---------------------------------------------------------------------------
// FUSED: blocks [0, SORTB) = sortb (phase B of bucket sort);
//        blocks [SORTB, SORTB+SLRB) = per-node attention scalars (slr).
// sortb needs only `pairs` (from k_bucket); slr needs only h16 (from GEMM) --
// independent roots, so they overlap instead of serializing two launches.
#define SORTB (kM * NBK)                       // 392
#define SLRB ((kN * kH + 255) / 256)           // 782
__global__ __launch_bounds__(256) void k_sortslr(const unsigned int* __restrict__ pairs,
                                                 const int* __restrict__ offs,
                                                 int* __restrict__ cur,
                                                 int* __restrict__ srcsort,
                                                 const unsigned short* __restrict__ h16,
                                                 const float* __restrict__ attn,
                                                 float* __restrict__ sl,
                                                 float* __restrict__ sr) {
    const int t = threadIdx.x;
    if (blockIdx.x < SORTB) {
        // ---- sortb: one block per (m,bucket); srcsort writes confined to a
        // 32 KB window with a single writer block ----
        const int m = blockIdx.x / NBK;
        const int bk = blockIdx.x - m * NBK;
        const int bs = bk << 9;
        const int be = (bs + 512 < kN) ? (bs + 512) : kN;
        const int* __restrict__ om = offs + m * (kN + 1);
        const int start = om[bs];
        const int end = om[be];
        int* __restrict__ cm = cur + m * kN;
        for (int c = start; c < end; c += 2048) {
            unsigned int v[8]; int pos[8]; bool ok[8];
#pragma unroll
            for (int j = 0; j < 8; j++) {
                const int idx = c + j * 256 + t;
                ok[j] = idx < end;
                v[j] = pairs[(size_t)m * kE + (ok[j] ? idx : start)];
            }
#pragma unroll
            for (int j = 0; j < 8; j++) {
                if (ok[j]) {
                    const int d = bs + (int)(v[j] >> 16);
                    pos[j] = om[d] + atomicAdd(&cm[d], 1);
                }
            }
#pragma unroll
            for (int j = 0; j < 8; j++)
                if (ok[j]) srcsort[(size_t)m * kE + pos[j]] = (int)(v[j] & 0xffffu);
        }
        return;
    }
    // ---- slr ----
    const int id = (blockIdx.x - SORTB) * 256 + t;
    if (id >= kN * kH) return;
    const int n = id >> 2;
    const int hh = id & 3;
    const unsigned int* hu =
        reinterpret_cast<const unsigned int*>(h16 + (size_t)n * kD + hh * kC);
    unsigned int u[16];
    uint4 u4;
#pragma unroll
    for (int i = 0; i < 4; i++) {
        u4 = reinterpret_cast<const uint4*>(hu)[i];
        u[i * 4 + 0] = u4.x; u[i * 4 + 1] = u4.y; u[i * 4 + 2] = u4.z; u[i * 4 + 3] = u4.w;
    }
    float f0[16], f1[16];
#pragma unroll
    for (int c = 0; c < 16; c++) {
        f0[c] = __uint_as_float(u[c] << 16);
        f1[c] = __uint_as_float(u[c] & 0xffff0000u);
    }
#pragma unroll
    for (int m = 0; m < kM; m++) {
        const float2* al = reinterpret_cast<const float2*>(attn + (m * kH + hh) * 2 * kC);
        const float2* ar = al + 16;
        float s0 = 0.f, s1 = 0.f;
#pragma unroll
        for (int c = 0; c < 16; c++) {
            const float2 a = al[c], r = ar[c];
            s0 += f0[c] * a.x + f1[c] * a.y;
            s1 += f0[c] * r.x + f1[c] * r.y;
        }
        sl[((size_t)m * kN + n) * kH + hh] = s0;
        sr[((size_t)m * kN + n) * kH + hh] = s1;
    }
}

// ---------------------------------------------------------------------------
// aggregation (R10: R9 + thinner tails).
// Every segment has one partial chunk (avg 8 live of 16 slots). R9 issued 16
// clamped gathers regardless; R10 splits the chunk body on a wave-uniform
// nb>=9 test into 16-gather and 8-gather variants (all indices compile-time,
// no scratch). Saves ~0.8M dead dst-row gathers (VMEM slots + L2 BW).
#define CH 16

#define AGG_BODY(GN)                                                            \
    {                                                                           \
        int sj[GN];                                                             \
        _Pragma("unroll")                                                       \
        for (int j = 0; j < GN; j++) {                                          \
            const int id = __builtin_amdgcn_readlane(my0, j);                   \
            sj[j] = (j < nb) ? id : dst;                                        \
        }                                                                       \
        unsigned int u[GN];                                                     \
        _Pragma("unroll")                                                       \
        for (int j = 0; j < GN; j++)                                            \
            u[j] = *reinterpret_cast<const unsigned int*>(                      \
                hb + (((size_t)(unsigned int)sj[j] << 8) + ebyte));             \
        float x = sl_h + srv;                                                   \
        x = x > 0.f ? x : 0.2f * x;            /* LeakyReLU(0.2) */             \
        const float w = (c + jj < cnt) ? __expf(x) : 0.f;                       \
        sum += w;                                                               \
        swts[m][l] = w;                                                         \
        __builtin_amdgcn_wave_barrier();                                        \
        const float4 w0 = *reinterpret_cast<const float4*>(&swts[m][hh * 16]);  \
        const float4 w1 = *reinterpret_cast<const float4*>(&swts[m][hh*16+4]);  \
        const float4 w2 = *reinterpret_cast<const float4*>(&swts[m][hh*16+8]);  \
        const float4 w3 = *reinterpret_cast<const float4*>(&swts[m][hh*16+12]); \
        __builtin_amdgcn_wave_barrier();                                        \
        my0 = my1;                                                              \
        my1 = sbase[c + 2 * CH + jj];                                           \
        srv = *reinterpret_cast<const float*>(                                  \
            srb + (((unsigned int)my0 << 4) + hbyte));                          \
        const float wj[16] = {w0.x, w0.y, w0.z, w0.w, w1.x, w1.y, w1.z, w1.w,   \
                              w2.x, w2.y, w2.z, w2.w, w3.x, w3.y, w3.z, w3.w};  \
        _Pragma("unroll")                                                       \
        for (int j = 0; j < GN; j++) {                                          \
            a0 += wj[j] * __uint_as_float(u[j] << 16);                          \
            a1 += wj[j] * __uint_as_float(u[j] & 0xffff0000u);                  \
        }                                                                       \
    }

__global__ __launch_bounds__(256) void k_agg(const unsigned short* __restrict__ h16,
                                             const float* __restrict__ sl,
                                             const float* __restrict__ sr,
                                             const int* __restrict__ offs,
                                             const int* __restrict__ srcsort,
                                             const float* __restrict__ ral,
                                             const float* __restrict__ rar,
                                             const float* __restrict__ rbias,
                                             float* __restrict__ out) {
    const int dst = blockIdx.x;
    const int t = threadIdx.x;
    const int m = t >> 6;
    const int l = t & 63;
    const int hh = l >> 4;        // head for this lane
    const int jj = l & 15;        // edge slot this lane computes the weight for
    const int e0 = l * 2;         // channel pair e0, e0+1

    __shared__ float smres[kM][kD];
    __shared__ float swts[kM][64];

    const int beg = offs[m * (kN + 1) + dst];
    const int cnt = offs[m * (kN + 1) + dst + 1] - beg;
    const float sl_h = sl[((size_t)m * kN + dst) * kH + hh];
    const int* __restrict__ sbase = srcsort + (size_t)m * kE + beg;
    const char* __restrict__ hb = (const char*)h16;
    const char* __restrict__ srb = (const char*)(sr + (size_t)m * kN * kH);
    const unsigned int ebyte = (unsigned int)(e0 << 1);
    const unsigned int hbyte = (unsigned int)(hh << 2);

    float sum = 0.f, a0 = 0.f, a1 = 0.f;

    // prologue prefetch (over-read safe: next segment ids are valid rows,
    // global slack is zeroed; dead slots get weight 0 and clamped gathers)
    int my0 = sbase[jj];
    int my1 = sbase[CH + jj];
    float srv = *reinterpret_cast<const float*>(
        srb + (((unsigned int)my0 << 4) + hbyte));

    for (int c = 0; c < cnt; c += CH) {
        const int nb = cnt - c;   // wave-uniform chunk occupancy
        if (nb >= 9) AGG_BODY(16) else AGG_BODY(8)
    }

    sum += __shfl_xor(sum, 1);
    sum += __shfl_xor(sum, 2);
    sum += __shfl_xor(sum, 4);
    sum += __shfl_xor(sum, 8);
    const float inv = 1.0f / (sum + 1e-16f);
    smres[m][e0] = a0 * inv;
    smres[m][e0 + 1] = a1 * inv;
    __syncthreads();

    if (m == 0) {
        const unsigned int ud = *reinterpret_cast<const unsigned int*>(
            hb + (((unsigned int)dst << 8) + ebyte));
        const float hd0 = __uint_as_float(ud << 16);
        const float hd1 = __uint_as_float(ud & 0xffff0000u);
        const float bl0 = fmaxf(hd0 * ral[e0], 0.f);
        const float bl1 = fmaxf(hd1 * ral[e0 + 1], 0.f);
        float emb0[5], emb1[5], beta[5];
#pragma unroll
        for (int r = 0; r < 5; r++) {
            const float x0 = (r < 4) ? smres[r][e0] : hd0;
            const float x1 = (r < 4) ? smres[r][e0 + 1] : hd1;
            emb0[r] = x0;
            emb1[r] = x1;
            const float br0 = fmaxf(x0 * rar[r * kD + e0], 0.f);
            const float br1 = fmaxf(x1 * rar[r * kD + e0 + 1], 0.f);
            float p = bl0 * br0 + bl1 * br1;
            p += __shfl_xor(p, 1);
            p += __shfl_xor(p, 2);
            p += __shfl_xor(p, 4);
            p += __shfl_xor(p, 8);
            beta[r] = p + rbias[r];
        }
        float mx = beta[0];
#pragma unroll
        for (int r = 1; r < 5; r++) mx = fmaxf(mx, beta[r]);
        float s = 0.f, wgt[5];
#pragma unroll
        for (int r = 0; r < 5; r++) { wgt[r] = __expf(beta[r] - mx); s += wgt[r]; }
        const float invb = 1.f / s;
        float o0 = 0.f, o1 = 0.f;
#pragma unroll
        for (int r = 0; r < 5; r++) { o0 += emb0[r] * wgt[r]; o1 += emb1[r] * wgt[r]; }
        out[(size_t)dst * kD + e0] = fmaxf(o0 * invb, 0.f);
        out[(size_t)dst * kD + e0 + 1] = fmaxf(o1 * invb, 0.f);
    }
}

// ---------------------------------------------------------------------------
extern "C" void kernel_launch(void* const* d_in, const int* in_sizes, int n_in,
                              void* d_out, int out_size, void* d_ws, size_t ws_size,
                              hipStream_t stream) {
    const float* feats = (const float*)d_in[0];
    const int* ei      = (const int*)d_in[1];
    const float* W     = (const float*)d_in[2];
    const float* b     = (const float*)d_in[3];
    const float* attn  = (const float*)d_in[4];
    const float* ral   = (const float*)d_in[5];
    const float* rar   = (const float*)d_in[6];
    const float* rbias = (const float*)d_in[7];
    float* out = (float*)d_out;

    char* ws = (char*)d_ws;
    size_t off = 0;
    auto alloc = [&](size_t bytes) -> void* {
        void* p = ws + off;
        off = (off + bytes + 255) & ~(size_t)255;
        return p;
    };
    unsigned short* h16 = (unsigned short*)alloc(sizeof(short) * (size_t)kN * kD); // 12.8 MB
    unsigned short* Wt16= (unsigned short*)alloc(sizeof(short) * (size_t)kD * kIN); // 64 KB
    float* sl   = (float*)alloc(sizeof(float) * (size_t)kM * kN * kH);         // 3.2 MB
    float* sr   = (float*)alloc(sizeof(float) * (size_t)kM * kN * kH);         // 3.2 MB
    int* cnt    = (int*)alloc(sizeof(int) * ((size_t)2 * kM * kN + 512));      // cnt+cur+bcur
    int* cur    = cnt + (size_t)kM * kN;
    int* bcur   = cnt + (size_t)2 * kM * kN;                                   // kM*NBK = 392
    int* offs   = (int*)alloc(sizeof(int) * (size_t)kM * (kN + 1));
    int* srcsort= (int*)alloc(sizeof(int) * ((size_t)kM * kE + 64));           // + zeroed slack
    unsigned int* pairs = (unsigned int*)alloc(sizeof(int) * (size_t)kM * kE); // 12.8 MB
    int* part   = (int*)alloc(sizeof(int) * SCBLOCKS);                         // scan flags

    hipMemsetAsync(cnt, 0, sizeof(int) * ((size_t)2 * kM * kN + 512), stream);
    hipMemsetAsync(part, 0, sizeof(int) * SCBLOCKS, stream);
    hipMemsetAsync(srcsort + (size_t)kM * kE, 0, sizeof(int) * 64, stream);
    k_wcast<<<kD, kIN, 0, stream>>>(W, Wt16);
    k_gemmcount<<<GEMMB + COUNTB, 256, 0, stream>>>(feats, Wt16, b, h16, ei, cnt);
    k_scan<<<SCBLOCKS, 256, 0, stream>>>(cnt, part, offs);
    k_bucket<<<kM * PAB, 256, 0, stream>>>(ei, offs, bcur, pairs);
    k_sortslr<<<SORTB + SLRB, 256, 0, stream>>>(pairs, offs, cur, srcsort,
                                                h16, attn, sl, sr);
    k_agg<<<kN, 256, 0, stream>>>(h16, sl, sr, offs, srcsort, ral, rar, rbias, out);
}

// Round 4
// 347.773 us; speedup vs baseline: 1.6468x; 1.4992x over previous
//
#include <hip/hip_runtime.h>
#include <math.h>

// Problem constants
#define kN 50000
#define kE 800000
#define kM 4
#define kH 4
#define kC 32
#define kIN 256
#define kD 128   // kH*kC

typedef __attribute__((ext_vector_type(8))) short bf16x8;
typedef __attribute__((ext_vector_type(4))) float f32x4;

__device__ __forceinline__ unsigned int f2bf_pack(float a, float b) {
    unsigned ua = __float_as_uint(a);
    ua += 0x7fffu + ((ua >> 16) & 1u);          // RNE
    unsigned ub = __float_as_uint(b);
    ub += 0x7fffu + ((ub >> 16) & 1u);
    return (ua >> 16) | (ub & 0xffff0000u);
}
__device__ __forceinline__ unsigned short f2bf(float x) {
    unsigned u = __float_as_uint(x);
    u += 0x7fffu + ((u >> 16) & 1u);
    return (unsigned short)(u >> 16);
}

// ---------------------------------------------------------------------------
// Bucket-major CSR: 98 buckets of 512 dsts per metapath, fixed capacity.
// Mean bucket fill = 8163, sigma ~90 -> BCAP 10240 is a >20-sigma margin.
#define NBK 98
#define BCAP 10240
#define MW (NBK * BCAP)               // per-m region: 1,003,520 slots
#define PAB ((kE + 4095) / 4096)      // 196 edge chunks per metapath

// ---------------------------------------------------------------------------
// Wt16[col][k] = bf16(W[k][col])  (128 cols x 256 k)
__global__ void k_wcast(const float* __restrict__ W, unsigned short* __restrict__ Wt16) {
    const int col = blockIdx.x;        // 0..127
    const int k = threadIdx.x;         // 0..255
    Wt16[(size_t)col * kIN + k] = f2bf(W[(size_t)k * kD + col]);
}

// ---------------------------------------------------------------------------
// FUSED: blocks [0,GEMMB) = MFMA bf16 GEMM (h16 = relu(feats@W+b));
//        blocks [GEMMB, GEMMB + kM*PAB) = bucket phase A (independent root:
//        needs only ei; LDS histogram over 98 buckets, ~98 global atomics per
//        block reserve space, pairs written into fixed-capacity bucket
//        windows -- no offs dependency, so it overlaps the GEMM).
// Replaces the old count kernel's 12.8M device-scope atomics entirely.
#define GEMMB ((kN + 127) / 128)          // 391
__global__ __launch_bounds__(256) void k_gemmbucket(const float* __restrict__ feats,
                                                    const unsigned short* __restrict__ Wt16,
                                                    const float* __restrict__ b,
                                                    unsigned short* __restrict__ h16,
                                                    const int* __restrict__ ei,
                                                    int* __restrict__ bcur,
                                                    unsigned int* __restrict__ pairs) {
    __shared__ unsigned short fr16[128 * 32];   // 8 KB: A chunk [row][32k]
    __shared__ int hist[NBK], h2[NBK], base_s[NBK];
    const int t = threadIdx.x;

    if (blockIdx.x >= GEMMB) {
        // ---- bucket phase A ----
        const int bi = blockIdx.x - GEMMB;
        const int m = bi / PAB;
        const int chunk = bi - m * PAB;
        const int e0 = chunk * 4096;
        for (int j = t; j < NBK; j += 256) { hist[j] = 0; h2[j] = 0; }
        __syncthreads();
        int src[16], dst[16];
#pragma unroll
        for (int i = 0; i < 16; i++) {
            const int e = e0 + i * 256 + t;
            const int eok = (e < kE) ? e : 0;
            src[i] = ei[(size_t)m * 2 * kE + eok];
            dst[i] = (e < kE) ? ei[(size_t)m * 2 * kE + kE + eok] : -1;
        }
#pragma unroll
        for (int i = 0; i < 16; i++)
            if (dst[i] >= 0) atomicAdd(&hist[dst[i] >> 9], 1);
        __syncthreads();
        for (int j = t; j < NBK; j += 256)
            base_s[j] = atomicAdd(&bcur[m * NBK + j], hist[j]);
        __syncthreads();
#pragma unroll
        for (int i = 0; i < 16; i++) {
            if (dst[i] >= 0) {
                const int bk = dst[i] >> 9;
                const int slot = base_s[bk] + atomicAdd(&h2[bk], 1);
                pairs[(size_t)m * MW + (size_t)bk * BCAP + slot] =
                    ((unsigned int)(dst[i] & 511) << 16) | (unsigned int)src[i];
            }
        }
        return;
    }

    // ---- MFMA GEMM ----
    const int lane = t & 63;
    const int wave = t >> 6;
    const int q = lane >> 4;           // quad 0..3
    const int m16 = lane & 15;
    const int wrow = (wave >> 1) * 64;
    const int wcol = (wave & 1) * 64;
    const int rowbase = blockIdx.x * 128;

    f32x4 acc[4][4];
#pragma unroll
    for (int i = 0; i < 4; i++)
#pragma unroll
        for (int j = 0; j < 4; j++) acc[i][j] = (f32x4){0.f, 0.f, 0.f, 0.f};

    const int srow = t >> 3;           // staging: 32 rows per pass
    const int sk4 = t & 7;             // float4 slot along k (8 slots = 32 k)

    for (int kc = 0; kc < kIN; kc += 32) {
        __syncthreads();
#pragma unroll
        for (int it = 0; it < 4; it++) {
            const int row = srow + it * 32;
            const int rg = rowbase + row;
            float4 v = make_float4(0.f, 0.f, 0.f, 0.f);
            if (rg < kN)
                v = *reinterpret_cast<const float4*>(feats + (size_t)rg * kIN + kc + sk4 * 4);
            uint2 p;
            p.x = f2bf_pack(v.x, v.y);
            p.y = f2bf_pack(v.z, v.w);
            *reinterpret_cast<uint2*>(&fr16[row * 32 + sk4 * 4]) = p;
        }
        __syncthreads();

        bf16x8 afr[4], bfr[4];
#pragma unroll
        for (int ri = 0; ri < 4; ri++)
            afr[ri] = *reinterpret_cast<const bf16x8*>(
                &fr16[(wrow + ri * 16 + m16) * 32 + q * 8]);
#pragma unroll
        for (int ci = 0; ci < 4; ci++)
            bfr[ci] = *reinterpret_cast<const bf16x8*>(
                Wt16 + (size_t)(wcol + ci * 16 + m16) * kIN + kc + q * 8);
#pragma unroll
        for (int ri = 0; ri < 4; ri++)
#pragma unroll
            for (int ci = 0; ci < 4; ci++)
                acc[ri][ci] = __builtin_amdgcn_mfma_f32_16x16x32_bf16(
                    afr[ri], bfr[ci], acc[ri][ci], 0, 0, 0);
    }

    float bcol[4];
#pragma unroll
    for (int ci = 0; ci < 4; ci++) bcol[ci] = b[wcol + ci * 16 + m16];

#pragma unroll
    for (int ri = 0; ri < 4; ri++) {
#pragma unroll
        for (int reg = 0; reg < 4; reg++) {
            const int row = rowbase + wrow + ri * 16 + q * 4 + reg;
            if (row < kN) {
#pragma unroll
                for (int ci = 0; ci < 4; ci++) {
                    const int col = wcol + ci * 16 + m16;
                    const float v = fmaxf(acc[ri][ci][reg] + bcol[ci], 0.f);
                    h16[(size_t)row * kD + col] = f2bf(v);
                }
            }
        }
    }
}

// ---------------------------------------------------------------------------
// FUSED: blocks [0, SORTB) = per-(m,bucket) LOCAL count+scan+place: LDS
//   hist[512] -> LDS scan -> LDS-atomic placement. Writes srcsort within the
//   bucket window, plus per-dst beg (offs) and count (cnta). Replaces the
//   global cnt atomics + k_scan + global cur atomics of the old pipeline.
// blocks [SORTB, SORTB+SLRB) = per-node attention scalars (slr; needs only
//   h16 -- independent root, overlaps the sort).
#define SORTB (kM * NBK)                       // 392
#define SLRB ((kN * kH + 255) / 256)           // 782
__global__ __launch_bounds__(256) void k_sortslr(const unsigned int* __restrict__ pairs,
                                                 const int* __restrict__ bcur,
                                                 int* __restrict__ offs,
                                                 int* __restrict__ cnta,
                                                 int* __restrict__ srcsort,
                                                 const unsigned short* __restrict__ h16,
                                                 const float* __restrict__ attn,
                                                 float* __restrict__ sl,
                                                 float* __restrict__ sr) {
    const int t = threadIdx.x;
    if (blockIdx.x < SORTB) {
        __shared__ int hist[512], pref[512], h2[512], wt[4];
        const int m = blockIdx.x / NBK;
        const int bk = blockIdx.x - m * NBK;
        const int bs = bk << 9;
        const int base = bk * BCAP;
        const int n = bcur[m * NBK + bk];      // exact bucket fill from phase A
        const unsigned int* __restrict__ pb = pairs + (size_t)m * MW + base;
        int* __restrict__ ss = srcsort + (size_t)m * MW + base;

        hist[t] = 0; hist[t + 256] = 0; h2[t] = 0; h2[t + 256] = 0;
        __syncthreads();

        // pass 1: per-dst histogram (8-deep batched reads)
        for (int c0 = 0; c0 < n; c0 += 2048) {
            unsigned int v[8]; bool ok[8];
#pragma unroll
            for (int j = 0; j < 8; j++) {
                const int idx = c0 + j * 256 + t;
                ok[j] = idx < n;
                v[j] = pb[ok[j] ? idx : 0];
            }
#pragma unroll
            for (int j = 0; j < 8; j++)
                if (ok[j]) atomicAdd(&hist[v[j] >> 16], 1);
        }
        __syncthreads();

        // scan 512 bins with 256 threads (2 bins/thread)
        const int lane = t & 63, wid = t >> 6;
        const int j0 = 2 * t, j1 = 2 * t + 1;
        const int h0 = hist[j0], h1 = hist[j1];
        const int s = h0 + h1;
        int incl = s;
#pragma unroll
        for (int d = 1; d < 64; d <<= 1) {
            const int x = __shfl_up(incl, d);
            if (lane >= d) incl += x;
        }
        if (lane == 63) wt[wid] = incl;
        __syncthreads();
        int woff = 0;
#pragma unroll
        for (int i = 0; i < 4; i++)
            if (i < wid) woff += wt[i];
        const int excl = woff + incl - s;
        pref[j0] = excl;
        pref[j1] = excl + h0;
        const int d0 = bs + j0, d1 = bs + j1;
        if (d0 < kN) { offs[m * kN + d0] = base + excl;       cnta[m * kN + d0] = h0; }
        if (d1 < kN) { offs[m * kN + d1] = base + excl + h0;  cnta[m * kN + d1] = h1; }
        __syncthreads();

        // pass 2: place (LDS atomics only)
        for (int c0 = 0; c0 < n; c0 += 2048) {
            unsigned int v[8]; bool ok[8];
#pragma unroll
            for (int j = 0; j < 8; j++) {
                const int idx = c0 + j * 256 + t;
                ok[j] = idx < n;
                v[j] = pb[ok[j] ? idx : 0];
            }
#pragma unroll
            for (int j = 0; j < 8; j++) {
                if (ok[j]) {
                    const int dl = (int)(v[j] >> 16);
                    const int pos = pref[dl] + atomicAdd(&h2[dl], 1);
                    ss[pos] = (int)(v[j] & 0xffffu);
                }
            }
        }
        return;
    }
    // ---- slr ----
    const int id = (blockIdx.x - SORTB) * 256 + t;
    if (id >= kN * kH) return;
    const int n = id >> 2;
    const int hh = id & 3;
    const unsigned int* hu =
        reinterpret_cast<const unsigned int*>(h16 + (size_t)n * kD + hh * kC);
    unsigned int u[16];
    uint4 u4;
#pragma unroll
    for (int i = 0; i < 4; i++) {
        u4 = reinterpret_cast<const uint4*>(hu)[i];
        u[i * 4 + 0] = u4.x; u[i * 4 + 1] = u4.y; u[i * 4 + 2] = u4.z; u[i * 4 + 3] = u4.w;
    }
    float f0[16], f1[16];
#pragma unroll
    for (int c = 0; c < 16; c++) {
        f0[c] = __uint_as_float(u[c] << 16);
        f1[c] = __uint_as_float(u[c] & 0xffff0000u);
    }
#pragma unroll
    for (int m = 0; m < kM; m++) {
        const float2* al = reinterpret_cast<const float2*>(attn + (m * kH + hh) * 2 * kC);
        const float2* ar = al + 16;
        float s0 = 0.f, s1 = 0.f;
#pragma unroll
        for (int c = 0; c < 16; c++) {
            const float2 a = al[c], r = ar[c];
            s0 += f0[c] * a.x + f1[c] * a.y;
            s1 += f0[c] * r.x + f1[c] * r.y;
        }
        sl[((size_t)m * kN + n) * kH + hh] = s0;
        sr[((size_t)m * kN + n) * kH + hh] = s1;
    }
}

// ---------------------------------------------------------------------------
// aggregation (R11: identical hot loop to R10; beg/cnt now sourced from the
// bucket-major offs/cnta arrays; inter-bucket gaps in srcsort are zeroed so
// the prologue over-read lands on id 0 (hot row) with weight 0).
#define CH 16

#define AGG_BODY(GN)                                                            \
    {                                                                           \
        int sj[GN];                                                             \
        _Pragma("unroll")                                                       \
        for (int j = 0; j < GN; j++) {                                          \
            const int id = __builtin_amdgcn_readlane(my0, j);                   \
            sj[j] = (j < nb) ? id : dst;                                        \
        }                                                                       \
        unsigned int u[GN];                                                     \
        _Pragma("unroll")                                                       \
        for (int j = 0; j < GN; j++)                                            \
            u[j] = *reinterpret_cast<const unsigned int*>(                      \
                hb + (((size_t)(unsigned int)sj[j] << 8) + ebyte));             \
        float x = sl_h + srv;                                                   \
        x = x > 0.f ? x : 0.2f * x;            /* LeakyReLU(0.2) */             \
        const float w = (c + jj < cnt) ? __expf(x) : 0.f;                       \
        sum += w;                                                               \
        swts[m][l] = w;                                                         \
        __builtin_amdgcn_wave_barrier();                                        \
        const float4 w0 = *reinterpret_cast<const float4*>(&swts[m][hh * 16]);  \
        const float4 w1 = *reinterpret_cast<const float4*>(&swts[m][hh*16+4]);  \
        const float4 w2 = *reinterpret_cast<const float4*>(&swts[m][hh*16+8]);  \
        const float4 w3 = *reinterpret_cast<const float4*>(&swts[m][hh*16+12]); \
        __builtin_amdgcn_wave_barrier();                                        \
        my0 = my1;                                                              \
        my1 = sbase[c + 2 * CH + jj];                                           \
        srv = *reinterpret_cast<const float*>(                                  \
            srb + (((unsigned int)my0 << 4) + hbyte));                          \
        const float wj[16] = {w0.x, w0.y, w0.z, w0.w, w1.x, w1.y, w1.z, w1.w,   \
                              w2.x, w2.y, w2.z, w2.w, w3.x, w3.y, w3.z, w3.w};  \
        _Pragma("unroll")                                                       \
        for (int j = 0; j < GN; j++) {                                          \
            a0 += wj[j] * __uint_as_float(u[j] << 16);                          \
            a1 += wj[j] * __uint_as_float(u[j] & 0xffff0000u);                  \
        }                                                                       \
    }

__global__ __launch_bounds__(256) void k_agg(const unsigned short* __restrict__ h16,
                                             const float* __restrict__ sl,
                                             const float* __restrict__ sr,
                                             const int* __restrict__ offs,
                                             const int* __restrict__ cnta,
                                             const int* __restrict__ srcsort,
                                             const float* __restrict__ ral,
                                             const float* __restrict__ rar,
                                             const float* __restrict__ rbias,
                                             float* __restrict__ out) {
    const int dst = blockIdx.x;
    const int t = threadIdx.x;
    const int m = t >> 6;
    const int l = t & 63;
    const int hh = l >> 4;        // head for this lane
    const int jj = l & 15;        // edge slot this lane computes the weight for
    const int e0 = l * 2;         // channel pair e0, e0+1

    __shared__ float smres[kM][kD];
    __shared__ float swts[kM][64];

    const int beg = offs[m * kN + dst];
    const int cnt = cnta[m * kN + dst];
    const float sl_h = sl[((size_t)m * kN + dst) * kH + hh];
    const int* __restrict__ sbase = srcsort + (size_t)m * MW + beg;
    const char* __restrict__ hb = (const char*)h16;
    const char* __restrict__ srb = (const char*)(sr + (size_t)m * kN * kH);
    const unsigned int ebyte = (unsigned int)(e0 << 1);
    const unsigned int hbyte = (unsigned int)(hh << 2);

    float sum = 0.f, a0 = 0.f, a1 = 0.f;

    // prologue prefetch (over-read safe: same-bucket successors are valid
    // ids; inter-bucket gaps and trailing slack are zeroed -> row 0; dead
    // slots get weight 0 and clamped gathers)
    int my0 = sbase[jj];
    int my1 = sbase[CH + jj];
    float srv = *reinterpret_cast<const float*>(
        srb + (((unsigned int)my0 << 4) + hbyte));

    for (int c = 0; c < cnt; c += CH) {
        const int nb = cnt - c;   // wave-uniform chunk occupancy
        if (nb >= 9) AGG_BODY(16) else AGG_BODY(8)
    }

    sum += __shfl_xor(sum, 1);
    sum += __shfl_xor(sum, 2);
    sum += __shfl_xor(sum, 4);
    sum += __shfl_xor(sum, 8);
    const float inv = 1.0f / (sum + 1e-16f);
    smres[m][e0] = a0 * inv;
    smres[m][e0 + 1] = a1 * inv;
    __syncthreads();

    if (m == 0) {
        const unsigned int ud = *reinterpret_cast<const unsigned int*>(
            hb + (((unsigned int)dst << 8) + ebyte));
        const float hd0 = __uint_as_float(ud << 16);
        const float hd1 = __uint_as_float(ud & 0xffff0000u);
        const float bl0 = fmaxf(hd0 * ral[e0], 0.f);
        const float bl1 = fmaxf(hd1 * ral[e0 + 1], 0.f);
        float emb0[5], emb1[5], beta[5];
#pragma unroll
        for (int r = 0; r < 5; r++) {
            const float x0 = (r < 4) ? smres[r][e0] : hd0;
            const float x1 = (r < 4) ? smres[r][e0 + 1] : hd1;
            emb0[r] = x0;
            emb1[r] = x1;
            const float br0 = fmaxf(x0 * rar[r * kD + e0], 0.f);
            const float br1 = fmaxf(x1 * rar[r * kD + e0 + 1], 0.f);
            float p = bl0 * br0 + bl1 * br1;
            p += __shfl_xor(p, 1);
            p += __shfl_xor(p, 2);
            p += __shfl_xor(p, 4);
            p += __shfl_xor(p, 8);
            beta[r] = p + rbias[r];
        }
        float mx = beta[0];
#pragma unroll
        for (int r = 1; r < 5; r++) mx = fmaxf(mx, beta[r]);
        float s = 0.f, wgt[5];
#pragma unroll
        for (int r = 0; r < 5; r++) { wgt[r] = __expf(beta[r] - mx); s += wgt[r]; }
        const float invb = 1.f / s;
        float o0 = 0.f, o1 = 0.f;
#pragma unroll
        for (int r = 0; r < 5; r++) { o0 += emb0[r] * wgt[r]; o1 += emb1[r] * wgt[r]; }
        out[(size_t)dst * kD + e0] = fmaxf(o0 * invb, 0.f);
        out[(size_t)dst * kD + e0 + 1] = fmaxf(o1 * invb, 0.f);
    }
}

// ---------------------------------------------------------------------------
extern "C" void kernel_launch(void* const* d_in, const int* in_sizes, int n_in,
                              void* d_out, int out_size, void* d_ws, size_t ws_size,
                              hipStream_t stream) {
    const float* feats = (const float*)d_in[0];
    const int* ei      = (const int*)d_in[1];
    const float* W     = (const float*)d_in[2];
    const float* b     = (const float*)d_in[3];
    const float* attn  = (const float*)d_in[4];
    const float* ral   = (const float*)d_in[5];
    const float* rar   = (const float*)d_in[6];
    const float* rbias = (const float*)d_in[7];
    float* out = (float*)d_out;

    char* ws = (char*)d_ws;
    size_t off = 0;
    auto alloc = [&](size_t bytes) -> void* {
        void* p = ws + off;
        off = (off + bytes + 255) & ~(size_t)255;
        return p;
    };
    unsigned short* h16 = (unsigned short*)alloc(sizeof(short) * (size_t)kN * kD); // 12.8 MB
    unsigned short* Wt16= (unsigned short*)alloc(sizeof(short) * (size_t)kD * kIN); // 64 KB
    float* sl   = (float*)alloc(sizeof(float) * (size_t)kM * kN * kH);         // 3.2 MB
    float* sr   = (float*)alloc(sizeof(float) * (size_t)kM * kN * kH);         // 3.2 MB
    int* cnta   = (int*)alloc(sizeof(int) * (size_t)kM * kN);                  // 0.8 MB
    int* offs   = (int*)alloc(sizeof(int) * (size_t)kM * kN);                  // 0.8 MB
    int* bcur   = (int*)alloc(sizeof(int) * (kM * NBK + 64));                  // 392
    int* srcsort= (int*)alloc(sizeof(int) * ((size_t)kM * MW + 64));           // 16.1 MB
    unsigned int* pairs = (unsigned int*)alloc(sizeof(int) * (size_t)kM * MW); // 16.1 MB

    hipMemsetAsync(bcur, 0, sizeof(int) * (kM * NBK + 64), stream);
    // zero srcsort so inter-bucket gaps / slack read as id 0 (valid hot row)
    hipMemsetAsync(srcsort, 0, sizeof(int) * ((size_t)kM * MW + 64), stream);
    k_wcast<<<kD, kIN, 0, stream>>>(W, Wt16);
    k_gemmbucket<<<GEMMB + kM * PAB, 256, 0, stream>>>(feats, Wt16, b, h16, ei,
                                                       bcur, pairs);
    k_sortslr<<<SORTB + SLRB, 256, 0, stream>>>(pairs, bcur, offs, cnta, srcsort,
                                                h16, attn, sl, sr);
    k_agg<<<kN, 256, 0, stream>>>(h16, sl, sr, offs, cnta, srcsort,
                                  ral, rar, rbias, out);
}